// Round 6
// baseline (387.570 us; speedup 1.0000x reference)
//
#include <hip/hip_runtime.h>

#define HIDDEN 32
#define FF 40
#define SEQ_T 512
#define RD 8     // ring depth; producer/consumer slot distance (disjoint mod 8)

typedef __attribute__((ext_vector_type(8))) short short8;
typedef __attribute__((ext_vector_type(4))) float float4v;
typedef __attribute__((ext_vector_type(4))) unsigned uint4v;
typedef __attribute__((ext_vector_type(2))) unsigned uint2v;

// ---------------------------------------------------------------------------
// R15 = R14 (1 producer + 3 consumer waves, K=128 packed 3-term MFMA,
// setprio(1) producer, 2x2 MFMA chains) + two critical-path cuts:
//  (1) A-frags PINNED in VGPRs via opaque asm: R14's VGPR_Count=60 proved the
//      compiler was re-loading all 12 A-frags from global EVERY step (48 VGPRs
//      of A can't fit in 60 total) -- 12 hidden VMEM ops + vmcnt waits on the
//      serial chain. The "+v" asm forces materialization and blocks remat.
//  (2) Ring dedup: the S_hi-dup region existed only for linear frag reads.
//      Frag READ addresses are per-lane -- point f2/f3 chunks back at the
//      original S_hi ushorts. Row 128->104 ushorts, store_s 7->5 b64 writes,
//      ring 34816->26624 B. Chunk table (ushort offs): f0={0,8,16,24},
//      f1={32,40,48,56}, f2={64,72,0,8}, f3={16,24,32,80}. Prep mapping
//      UNCHANGED; product set identical; precision identical.
// ---------------------------------------------------------------------------

__global__ __launch_bounds__(256, 1) void rnn_prep(
    const float* __restrict__ W1hh, const float* __restrict__ b1hh,
    const float* __restrict__ W2hh, const float* __restrict__ b2hh,
    const float* __restrict__ W1ho, const float* __restrict__ b1ho,
    unsigned short* __restrict__ acatP)
{
    const int idx = blockIdx.x * 256 + threadIdx.x;
    if (idx >= 96 * 128) return;
    const int mrow = idx >> 7, s = idx & 127;

    // slot -> (contraction col, plane): plane 0 = hi(trunc), 1 = lo(RNE)
    int kcol, plane;
    if (s < 40)       { kcol = s;            plane = 0; }  // Ah x S_hi
    else if (s < 80)  { kcol = s - 40;       plane = 0; }  // Ah x S_lo
    else if (s < 120) { kcol = s - 80;       plane = 1; }  // Al x S_hi
    else if (s < 124) { kcol = 40 + (s & 1); plane = 0; }  // Ah_u, Ah_b
    else if (s < 126) { kcol = 40 + (s & 1); plane = 1; }  // Al_u, Al_b
    else { acatP[idx] = 0; return; }

    const bool hh = mrow < 48;
    const int col = hh ? mrow : mrow - 48;
    float val = 0.f;
    if (col < FF) {
        const float* W1 = hh ? W1hh : W1ho;
        const float* b1 = hh ? b1hh : b1ho;
        if (kcol < FF) {
            for (int i = 0; i < HIDDEN; ++i)
                val = __builtin_fmaf(W2hh[kcol * HIDDEN + i], W1[i * FF + col], val);
        } else if (kcol == 40) {
            val = W1[HIDDEN * FF + col];
        } else {  // kcol == 41: folded bias channel
            val = b1[col];
            for (int i = 0; i < HIDDEN; ++i)
                val = __builtin_fmaf(b2hh[i], W1[i * FF + col], val);
        }
    }
    const unsigned vb = __builtin_bit_cast(unsigned, val);
    const unsigned short hi = (unsigned short)(vb >> 16);
    unsigned short out;
    if (plane == 0) {
        out = hi;
    } else {
        const float hif = __builtin_bit_cast(float, (unsigned)hi << 16);
        const float lo = val - hif;
        const unsigned lb = __builtin_bit_cast(unsigned, lo);
        out = (unsigned short)((lb + 0x7FFFu + ((lb >> 16) & 1u)) >> 16);
    }
    acatP[idx] = out;
}

__device__ __forceinline__ float sigmoid_fast(float x) {
    const float e = __builtin_amdgcn_exp2f(-x * 1.44269504088896341f);
    return __builtin_amdgcn_rcpf(1.0f + e);
}

// dword [hi16(v) : round-bf16(v - hi)] packer (u-channel)
__device__ __forceinline__ unsigned splitpack(float v) {
    const unsigned b = __builtin_bit_cast(unsigned, v);
    const unsigned hif = b & 0xFFFF0000u;
    const float rr = v - __builtin_bit_cast(float, hif);
    unsigned rb = __builtin_bit_cast(unsigned, rr) + 0x8000u;
    return __builtin_amdgcn_perm(b, rb, 0x07060302u);
}

// packs [bf16(hi) : bf16(lo)] with RNE; first operand lands in the LOW ushort
__device__ __forceinline__ unsigned cvt_pk_bf16(float lo, float hi) {
    unsigned r;
    asm("v_cvt_pk_bf16_f32 %0, %1, %2" : "=v"(r) : "v"(lo), "v"(hi));
    return r;
}

__global__ __launch_bounds__(256, 4) void rnn_main(
    const float* __restrict__ inputs,
    const unsigned short* __restrict__ acatP,
    const float* __restrict__ W1hh, const float* __restrict__ b1hh,
    const float* __restrict__ W1ho, const float* __restrict__ b1ho,
    const float* __restrict__ W2ho, const float* __restrict__ b2ho,
    float* __restrict__ ys)
{
    // 104-ushort rows (208 B, 16B-aligned): Sh[40] | Sl[40] | ub[8] | pad[16]
    __shared__ __align__(16) unsigned short ring[RD][16][104];   // 26624 B

    const int tid = threadIdx.x;
    const int wv  = __builtin_amdgcn_readfirstlane(tid >> 6);  // 0=hh prod, 1..3=ho cons
    const int l = tid & 63;
    const int r = l & 15;        // batch row within tile
    const int g = l >> 4;        // quad
    const size_t rowbase = (size_t)(blockIdx.x * 16 + r) * SEQ_T;
    const float* __restrict__ in_row = inputs + rowbase;

    // producer wave gets issue priority: its serial recurrence IS the clock
    if (wv == 0) __builtin_amdgcn_s_setprio(1);

    // ---- zero the ring (ub pad + tail slots must read as 0 forever) ----
    {
        uint4v* zp = (uint4v*)&ring[0][0][0];
        const uint4v z4 = {0u, 0u, 0u, 0u};
#pragma unroll
        for (int i = 0; i < 7; ++i) {
            const int idx = tid + 256 * i;
            if (idx < 1664) zp[idx] = z4;    // 1664 * 16 B = 26624 B
        }
    }

    // ---- A-frags: producer hh m-tiles 0-2, consumers ho m-tiles 3-5 ----
    uint4v AR[3][4];
    const int mb = (wv == 0) ? 0 : 3;
#pragma unroll
    for (int mt = 0; mt < 3; ++mt)
#pragma unroll
        for (int ks = 0; ks < 4; ++ks)
            AR[mt][ks] = *(const uint4v*)(acatP + ((mb + mt) * 16 + r) * 128 + ks * 32 + g * 8);
    // pin in VGPRs: opaque asm "writes" each frag so the compiler cannot
    // rematerialize the global loads inside the step loop
#pragma unroll
    for (int mt = 0; mt < 3; ++mt)
#pragma unroll
        for (int ks = 0; ks < 4; ++ks)
            asm volatile("" : "+v"(AR[mt][ks]));

    float w2o_l[3][4];
#pragma unroll
    for (int mt = 0; mt < 3; ++mt)
#pragma unroll
        for (int q = 0; q < 4; ++q) {
            const int j = 16 * mt + 4 * g + q;
            w2o_l[mt][q] = (j < FF) ? W2ho[j] : 0.f;
        }
    const float b2o = b2ho[0];
    const bool out16 = (l < 16);

    // frag chunk offsets (ushorts within a row): f2/f3 re-read Sh (no dup)
    const int o0 = g * 8;
    const int o1 = 32 + g * 8;
    const int o2 = (g < 2) ? 64 + g * 8 : (g - 2) * 8;
    const int o3 = (g < 3) ? 16 + g * 8 : 80;

    auto load_frags = [&](int sl, short8 (&f)[4]) {
        const unsigned short* p = &ring[sl][r][0];
        f[0] = *(const short8*)(p + o0);
        f[1] = *(const short8*)(p + o1);
        f[2] = *(const short8*)(p + o2);
        f[3] = *(const short8*)(p + o3);
    };

    // two independent 2-deep MFMA chains per m-tile + one vector add
    auto do_mfma = [&](const short8 (&f)[4], float4v (&acc)[3]) {
#pragma unroll
        for (int mt = 0; mt < 3; ++mt) {
            float4v a = (float4v)0.f, b = (float4v)0.f;
            a = __builtin_amdgcn_mfma_f32_16x16x32_bf16(
                    __builtin_bit_cast(short8, AR[mt][0]), f[0], a, 0, 0, 0);
            b = __builtin_amdgcn_mfma_f32_16x16x32_bf16(
                    __builtin_bit_cast(short8, AR[mt][2]), f[2], b, 0, 0, 0);
            a = __builtin_amdgcn_mfma_f32_16x16x32_bf16(
                    __builtin_bit_cast(short8, AR[mt][1]), f[1], a, 0, 0, 0);
            b = __builtin_amdgcn_mfma_f32_16x16x32_bf16(
                    __builtin_bit_cast(short8, AR[mt][3]), f[3], b, 0, 0, 0);
            acc[mt] = a + b;
        }
    };

    // sigmoid + split-pack + ring store: Sh @ dword 2j, Sl @ dword 20+2j,
    // ub dwords @ 40..42 (g==3 quad). No dup region.
    auto store_s = [&](int slot, const float4v (&z)[3], unsigned upk) {
        unsigned* bp = (unsigned*)&ring[slot][r][0];
#pragma unroll
        for (int mt = 0; mt < 3; ++mt) {
            const float s0 = sigmoid_fast(z[mt][0]);
            const float s1 = sigmoid_fast(z[mt][1]);
            const float s2 = sigmoid_fast(z[mt][2]);
            const float s3 = sigmoid_fast(z[mt][3]);
            const unsigned h01 = cvt_pk_bf16(s0, s1);
            const unsigned h23 = cvt_pk_bf16(s2, s3);
            const float r0 = s0 - __builtin_bit_cast(float, h01 << 16);
            const float r1 = s1 - __builtin_bit_cast(float, h01 & 0xFFFF0000u);
            const float r2 = s2 - __builtin_bit_cast(float, h23 << 16);
            const float r3 = s3 - __builtin_bit_cast(float, h23 & 0xFFFF0000u);
            const unsigned l01 = cvt_pk_bf16(r0, r1);
            const unsigned l23 = cvt_pk_bf16(r2, r3);
            const int j = 4 * mt + g;
            if (j < 10) {
                uint2v hp, lp;
                hp.x = h01; hp.y = h23;
                lp.x = l01; lp.y = l23;
                *(uint2v*)(bp + 2 * j) = hp;        // S_hi
                *(uint2v*)(bp + 20 + 2 * j) = lp;   // S_lo
            }
        }
        if (g == 3) {
            uint2v up;
            up.x = (upk >> 16) | 0x3F800000u;   // [u_hi : bf16(1.0)]
            up.y = upk & 0xFFFFu;               // [u_lo : 0]
            *(uint2v*)(bp + 40) = up;           // ushorts 80..83
            bp[42] = up.x;                      // ushorts 84,85 (dup for Al)
        }
    };

    __syncthreads();   // zeroing complete before prologue writes slot 0

    // ---- prologue: t = 0 ----
    float uc[3];
    if (wv == 0) {
        const float u0 = in_row[0];
        float4v z[3];
#pragma unroll
        for (int mt = 0; mt < 3; ++mt)
#pragma unroll
            for (int q = 0; q < 4; ++q) {
                const int n = 16 * mt + 4 * g + q;
                const int nc = n < FF ? n : FF - 1;
                z[mt][q] = __builtin_fmaf(u0, W1hh[HIDDEN * FF + nc], b1hh[nc]);
            }
        store_s(0, z, splitpack(in_row[1]));   // slot 0 = S(0) + u(1)
        uc[0] = in_row[2]; uc[1] = in_row[3]; uc[2] = in_row[4];
    } else if (wv == 1) {
        const float u0 = in_row[0];
        float op = 0.f;
#pragma unroll
        for (int mt = 0; mt < 3; ++mt)
#pragma unroll
            for (int q = 0; q < 4; ++q) {
                const int n = 16 * mt + 4 * g + q;
                const int nc = n < FF ? n : FF - 1;
                const float so = sigmoid_fast(
                    __builtin_fmaf(u0, W1ho[HIDDEN * FF + nc], b1ho[nc]));
                op = __builtin_fmaf(so, w2o_l[mt][q], op);
            }
        op += __shfl_xor(op, 16);
        op += __shfl_xor(op, 32);
        if (out16) ys[rowbase] = op + b2o;
    }
    __syncthreads();

    // ---- phase loop: wave0 runs steps [3p+1..3p+3]; wave w (1..3) runs the
    // single step t = 3p-2+(w-1)  (covers every t in 1..511 exactly once) ----
    for (int p = 0; p < 172; ++p) {
        if (wv == 0) {
            const int tb = 3 * p + 1;
            float un[3];
#pragma unroll
            for (int i = 0; i < 3; ++i) {
                int tn = tb + 4 + i; tn = tn < SEQ_T ? tn : SEQ_T - 1;
                un[i] = in_row[tn];     // u for next phase
            }
#pragma unroll
            for (int i = 0; i < 3; ++i) {
                const int t = tb + i;
                if (t < SEQ_T) {
                    short8 f[4];
                    load_frags((t - 1) & (RD - 1), f);
                    float4v z[3];
                    do_mfma(f, z);
                    store_s(t & (RD - 1), z, splitpack(uc[i]));
                }
            }
            uc[0] = un[0]; uc[1] = un[1]; uc[2] = un[2];
        } else {
            const int t = 3 * p - 2 + (wv - 1);
            if (t >= 1 && t < SEQ_T) {
                short8 f[4];
                load_frags((t - 1) & (RD - 1), f);
                float4v acc[3];
                do_mfma(f, acc);
                float op = 0.f;
#pragma unroll
                for (int mt = 0; mt < 3; ++mt)
#pragma unroll
                    for (int q = 0; q < 4; ++q)
                        op = __builtin_fmaf(sigmoid_fast(acc[mt][q]),
                                            w2o_l[mt][q], op);
                op += __shfl_xor(op, 16);
                op += __shfl_xor(op, 32);
                if (out16) ys[rowbase + t] = op + b2o;
            }
        }
        __syncthreads();
    }
}

extern "C" void kernel_launch(void* const* d_in, const int* in_sizes, int n_in,
                              void* d_out, int out_size, void* d_ws, size_t ws_size,
                              hipStream_t stream) {
    const float* inputs = (const float*)d_in[0];
    const float* W1hh   = (const float*)d_in[1];
    const float* b1hh   = (const float*)d_in[2];
    const float* W2hh   = (const float*)d_in[3];
    const float* b2hh   = (const float*)d_in[4];
    const float* W1ho   = (const float*)d_in[5];
    const float* b1ho   = (const float*)d_in[6];
    const float* W2ho   = (const float*)d_in[7];
    const float* b2ho   = (const float*)d_in[8];
    float* ys = (float*)d_out;

    unsigned short* acatP = (unsigned short*)d_ws;    // 96*128 ushorts

    const int B = in_sizes[0] / SEQ_T;   // 16384

    rnn_prep<<<(96 * 128 + 255) / 256, 256, 0, stream>>>(
        W1hh, b1hh, W2hh, b2hh, W1ho, b1ho, acatP);

    const int blocks = B / 16;           // 1024 blocks x 4 waves (1 hh + 3 ho)
    rnn_main<<<blocks, 256, 0, stream>>>(
        inputs, acatP, W1hh, b1hh, W1ho, b1ho, W2ho, b2ho, ys);
}

// Round 8
// 346.488 us; speedup vs baseline: 1.1186x; 1.1186x over previous
//
#include <hip/hip_runtime.h>

#define HIDDEN 32
#define FF 40
#define SEQ_T 512
#define RD 8     // ring depth; producer/consumer slot distance (disjoint mod 8)

typedef _Float16 half8 __attribute__((ext_vector_type(8)));
typedef __attribute__((ext_vector_type(4))) float float4v;
typedef __attribute__((ext_vector_type(4))) unsigned uint4v;
typedef __attribute__((ext_vector_type(2))) unsigned uint2v;

// ---------------------------------------------------------------------------
// R17 = R16 with the cvt_pkrtz type fix (builtin returns __fp16x2, not
// _Float16x2; bit_cast via the builtin's own type).
// Single-plane FP16 scheme: the 3-term bf16 hi/lo split (K=128) is replaced
// by one fp16 plane (K=64): fp16's 11-bit mantissa gives ~2^-12 per-element
// error; fresh z-error ~1e-4 RMS, recurrence RMS-gain ~0.2 (contractive) --
// fits the 1.16e-2 threshold with ~10x margin.
// Per wave-step: MFMA 12->6, ds_read 4->2, ds_write ~5->2.5, pack 24 ops ->
// 6 v_cvt_pkrtz; K-layout [S(40) | u(1) | 1.0(1) | 0-pad(22)].
// Ring row 72 ushorts (144 B): bank span 4(r+g) mod 32 -> 2-way max (free).
// Structure = R14: wave0 hh producer (3 steps/phase, setprio(1)); waves 1-3
// ho consumers (1 step each); RD=8 ring, 1 barrier/phase; ring zeroed once
// (slots 42..71 must read 0 forever; 0 x garbage-NaN would poison MFMA).
// ---------------------------------------------------------------------------

__global__ __launch_bounds__(256, 1) void rnn_prep(
    const float* __restrict__ W1hh, const float* __restrict__ b1hh,
    const float* __restrict__ W2hh, const float* __restrict__ b2hh,
    const float* __restrict__ W1ho, const float* __restrict__ b1ho,
    unsigned short* __restrict__ acatP)
{
    const int idx = blockIdx.x * 256 + threadIdx.x;
    if (idx >= 96 * 64) return;
    const int mrow = idx >> 6, s = idx & 63;

    const bool hh = mrow < 48;
    const int col = hh ? mrow : mrow - 48;
    float val = 0.f;
    if (col < FF && s < 42) {
        const float* W1 = hh ? W1hh : W1ho;
        const float* b1 = hh ? b1hh : b1ho;
        if (s < FF) {                 // A[s, col] = (W2hh^T W1)[s, col]
            for (int i = 0; i < HIDDEN; ++i)
                val = __builtin_fmaf(W2hh[s * HIDDEN + i], W1[i * FF + col], val);
        } else if (s == 40) {         // u-channel weight
            val = W1[HIDDEN * FF + col];
        } else {                      // s == 41: folded bias channel
            val = b1[col];
            for (int i = 0; i < HIDDEN; ++i)
                val = __builtin_fmaf(b2hh[i], W1[i * FF + col], val);
        }
    }
    const _Float16 hv = (_Float16)val;   // RNE
    acatP[idx] = __builtin_bit_cast(unsigned short, hv);
}

__device__ __forceinline__ float sigmoid_fast(float x) {
    const float e = __builtin_amdgcn_exp2f(-x * 1.44269504088896341f);
    return __builtin_amdgcn_rcpf(1.0f + e);
}

// packed f32->f16 (RTZ), a lands in the LOW half
__device__ __forceinline__ unsigned cvt_pkrtz_u(float a, float b) {
    auto h = __builtin_amdgcn_cvt_pkrtz(a, b);   // __fp16 ext_vector(2)
    return __builtin_bit_cast(unsigned, h);
}

__global__ __launch_bounds__(256, 4) void rnn_main(
    const float* __restrict__ inputs,
    const unsigned short* __restrict__ acatP,
    const float* __restrict__ W1hh, const float* __restrict__ b1hh,
    const float* __restrict__ W1ho, const float* __restrict__ b1ho,
    const float* __restrict__ W2ho, const float* __restrict__ b2ho,
    float* __restrict__ ys)
{
    // 72-ushort rows (144 B): S[40] | u | 1.0 | pad[30]; bank span 4(r+g)%32
    __shared__ __align__(16) unsigned short ring[RD][16][72];   // 18432 B

    const int tid = threadIdx.x;
    const int wv  = __builtin_amdgcn_readfirstlane(tid >> 6);  // 0=hh prod, 1..3=ho cons
    const int l = tid & 63;
    const int r = l & 15;        // batch row within tile
    const int g = l >> 4;        // quad
    const size_t rowbase = (size_t)(blockIdx.x * 16 + r) * SEQ_T;
    const float* __restrict__ in_row = inputs + rowbase;

    // producer wave gets issue priority: its serial recurrence IS the clock
    if (wv == 0) __builtin_amdgcn_s_setprio(1);

    // ---- zero the ring (pad slots 42..71 must read as 0 forever) ----
    {
        uint4v* zp = (uint4v*)&ring[0][0][0];
        const uint4v z4 = {0u, 0u, 0u, 0u};
#pragma unroll
        for (int i = 0; i < 5; ++i) {
            const int idx = tid + 256 * i;
            if (idx < 1152) zp[idx] = z4;    // 1152 * 16 B = 18432 B
        }
    }

    // ---- A-frags: producer hh m-tiles 0-2, consumers ho m-tiles 3-5 ----
    half8 A[3][2];
    const int mb = (wv == 0) ? 0 : 3;
#pragma unroll
    for (int mt = 0; mt < 3; ++mt)
#pragma unroll
        for (int ks = 0; ks < 2; ++ks)
            A[mt][ks] = *(const half8*)(acatP + ((mb + mt) * 16 + r) * 64 + ks * 32 + g * 8);

    float w2o_l[3][4];
#pragma unroll
    for (int mt = 0; mt < 3; ++mt)
#pragma unroll
        for (int q = 0; q < 4; ++q) {
            const int j = 16 * mt + 4 * g + q;
            w2o_l[mt][q] = (j < FF) ? W2ho[j] : 0.f;
        }
    const float b2o = b2ho[0];
    const bool out16 = (l < 16);

    auto load_frags = [&](int sl, half8 (&f)[2]) {
        const unsigned short* p = &ring[sl][r][0];
        f[0] = *(const half8*)(p + g * 8);
        f[1] = *(const half8*)(p + 32 + g * 8);
    };

    // two independent 1-deep MFMA chains per m-tile + one vector add
    auto do_mfma = [&](const half8 (&f)[2], float4v (&acc)[3]) {
#pragma unroll
        for (int mt = 0; mt < 3; ++mt) {
            float4v a = (float4v)0.f, b = (float4v)0.f;
            a = __builtin_amdgcn_mfma_f32_16x16x32_f16(A[mt][0], f[0], a, 0, 0, 0);
            b = __builtin_amdgcn_mfma_f32_16x16x32_f16(A[mt][1], f[1], b, 0, 0, 0);
            acc[mt] = a + b;
        }
    };

    // sigmoid + fp16 pack + ring store: S halves 4j..4j+3 at dwords 2j,2j+1
    // (j = 4mt+g < 10); u/bias dword 20 written by the g==3 quad
    auto store_s = [&](int slot, const float4v (&z)[3], float u_next) {
        unsigned* bp = (unsigned*)&ring[slot][r][0];
#pragma unroll
        for (int mt = 0; mt < 3; ++mt) {
            const float s0 = sigmoid_fast(z[mt][0]);
            const float s1 = sigmoid_fast(z[mt][1]);
            const float s2 = sigmoid_fast(z[mt][2]);
            const float s3 = sigmoid_fast(z[mt][3]);
            const unsigned p01 = cvt_pkrtz_u(s0, s1);
            const unsigned p23 = cvt_pkrtz_u(s2, s3);
            const int j = 4 * mt + g;
            if (j < 10) {
                uint2v hp;
                hp.x = p01; hp.y = p23;
                *(uint2v*)(bp + 2 * j) = hp;
            }
        }
        if (g == 3) bp[20] = cvt_pkrtz_u(u_next, 1.0f);   // [1.0h : u] halves 40,41
    };

    __syncthreads();   // zeroing complete before prologue writes slot 0

    // ---- prologue: t = 0 ----
    float uc[3];
    if (wv == 0) {
        const float u0 = in_row[0];
        float4v z[3];
#pragma unroll
        for (int mt = 0; mt < 3; ++mt)
#pragma unroll
            for (int q = 0; q < 4; ++q) {
                const int n = 16 * mt + 4 * g + q;
                const int nc = n < FF ? n : FF - 1;
                z[mt][q] = __builtin_fmaf(u0, W1hh[HIDDEN * FF + nc], b1hh[nc]);
            }
        store_s(0, z, in_row[1]);   // slot 0 = S(0) + u(1)
        uc[0] = in_row[2]; uc[1] = in_row[3]; uc[2] = in_row[4];
    } else if (wv == 1) {
        const float u0 = in_row[0];
        float op = 0.f;
#pragma unroll
        for (int mt = 0; mt < 3; ++mt)
#pragma unroll
            for (int q = 0; q < 4; ++q) {
                const int n = 16 * mt + 4 * g + q;
                const int nc = n < FF ? n : FF - 1;
                const float so = sigmoid_fast(
                    __builtin_fmaf(u0, W1ho[HIDDEN * FF + nc], b1ho[nc]));
                op = __builtin_fmaf(so, w2o_l[mt][q], op);
            }
        op += __shfl_xor(op, 16);
        op += __shfl_xor(op, 32);
        if (out16) ys[rowbase] = op + b2o;
    }
    __syncthreads();

    // ---- phase loop: wave0 runs steps [3p+1..3p+3]; wave w (1..3) runs the
    // single step t = 3p-2+(w-1)  (covers every t in 1..511 exactly once) ----
    for (int p = 0; p < 172; ++p) {
        if (wv == 0) {
            const int tb = 3 * p + 1;
            float un[3];
#pragma unroll
            for (int i = 0; i < 3; ++i) {
                int tn = tb + 4 + i; tn = tn < SEQ_T ? tn : SEQ_T - 1;
                un[i] = in_row[tn];     // u for next phase
            }
#pragma unroll
            for (int i = 0; i < 3; ++i) {
                const int t = tb + i;
                if (t < SEQ_T) {
                    half8 f[2];
                    load_frags((t - 1) & (RD - 1), f);
                    float4v z[3];
                    do_mfma(f, z);
                    store_s(t & (RD - 1), z, uc[i]);
                }
            }
            uc[0] = un[0]; uc[1] = un[1]; uc[2] = un[2];
        } else {
            const int t = 3 * p - 2 + (wv - 1);
            if (t >= 1 && t < SEQ_T) {
                half8 f[2];
                load_frags((t - 1) & (RD - 1), f);
                float4v acc[3];
                do_mfma(f, acc);
                float op = 0.f;
#pragma unroll
                for (int mt = 0; mt < 3; ++mt)
#pragma unroll
                    for (int q = 0; q < 4; ++q)
                        op = __builtin_fmaf(sigmoid_fast(acc[mt][q]),
                                            w2o_l[mt][q], op);
                op += __shfl_xor(op, 16);
                op += __shfl_xor(op, 32);
                if (out16) ys[rowbase + t] = op + b2o;
            }
        }
        __syncthreads();
    }
}

extern "C" void kernel_launch(void* const* d_in, const int* in_sizes, int n_in,
                              void* d_out, int out_size, void* d_ws, size_t ws_size,
                              hipStream_t stream) {
    const float* inputs = (const float*)d_in[0];
    const float* W1hh   = (const float*)d_in[1];
    const float* b1hh   = (const float*)d_in[2];
    const float* W2hh   = (const float*)d_in[3];
    const float* b2hh   = (const float*)d_in[4];
    const float* W1ho   = (const float*)d_in[5];
    const float* b1ho   = (const float*)d_in[6];
    const float* W2ho   = (const float*)d_in[7];
    const float* b2ho   = (const float*)d_in[8];
    float* ys = (float*)d_out;

    unsigned short* acatP = (unsigned short*)d_ws;    // 96*64 ushorts (fp16)

    const int B = in_sizes[0] / SEQ_T;   // 16384

    rnn_prep<<<(96 * 64 + 255) / 256, 256, 0, stream>>>(
        W1hh, b1hh, W2hh, b2hh, W1ho, b1ho, acatP);

    const int blocks = B / 16;           // 1024 blocks x 4 waves (1 hh + 3 ho)
    rnn_main<<<blocks, 256, 0, stream>>>(
        inputs, acatP, W1hh, b1hh, W1ho, b1ho, W2ho, b2ho, ys);
}